// Round 1
// baseline (424.267 us; speedup 1.0000x reference)
//
#include <hip/hip_runtime.h>
#include <cstdint>

typedef __attribute__((ext_vector_type(8))) short short8;
typedef __attribute__((ext_vector_type(4))) float floatx4;

__device__ __forceinline__ unsigned short f2bf(float f) {
  unsigned int u = __float_as_uint(f);
  u += 0x7fffu + ((u >> 16) & 1u);   // RNE, finite inputs
  return (unsigned short)(u >> 16);
}
__device__ __forceinline__ float bf2f(unsigned short h) {
  return __uint_as_float(((unsigned int)h) << 16);
}

// ---------------- GroupNorm stats: one block per (b, g) --------------------
__global__ __launch_bounds__(256) void gn_stats_kernel(
    const float* __restrict__ x, const float* __restrict__ gamma,
    const float* __restrict__ beta, float* __restrict__ scale,
    float* __restrict__ shift) {
  const int b = blockIdx.x >> 5;
  const int g = blockIdx.x & 31;
  const float4* xp = (const float4*)(x + ((long long)(b * 512 + g * 16)) * 4096);
  float s = 0.f, ss = 0.f;
  for (int i = threadIdx.x; i < 16384; i += 256) {  // 16 ch * 4096 / 4
    float4 v = xp[i];
    s  += v.x + v.y + v.z + v.w;
    ss += v.x * v.x + v.y * v.y + v.z * v.z + v.w * v.w;
  }
  for (int off = 32; off; off >>= 1) { s += __shfl_down(s, off); ss += __shfl_down(ss, off); }
  __shared__ float sb[8];
  const int lane = threadIdx.x & 63, wave = threadIdx.x >> 6;
  if (lane == 0) { sb[wave] = s; sb[4 + wave] = ss; }
  __syncthreads();
  if (threadIdx.x < 16) {
    const float S  = sb[0] + sb[1] + sb[2] + sb[3];
    const float SS = sb[4] + sb[5] + sb[6] + sb[7];
    const float mean = S * (1.f / 65536.f);
    const float var  = SS * (1.f / 65536.f) - mean * mean;
    const float inv  = rsqrtf(var + 1e-5f);
    const int c = g * 16 + threadIdx.x;
    const float sc = gamma[c] * inv;
    scale[b * 512 + c] = sc;
    shift[b * 512 + c] = beta[c] - mean * sc;
  }
}

// ---------------- weights fp32 -> bf16 -------------------------------------
__global__ __launch_bounds__(256) void wcvt_kernel(
    const float* __restrict__ wq, const float* __restrict__ wk,
    const float* __restrict__ wv, unsigned short* __restrict__ w16) {
  const float* src = (blockIdx.y == 0) ? wq : (blockIdx.y == 1) ? wk : wv;
  unsigned short* dst = w16 + (long long)blockIdx.y * 262144;
  const int i = blockIdx.x * 256 + threadIdx.x;  // * 4 elems
  float4 v = *((const float4*)src + i);
  ushort4 o;
  o.x = f2bf(v.x); o.y = f2bf(v.y); o.z = f2bf(v.z); o.w = f2bf(v.w);
  *((ushort4*)dst + i) = o;
}

// -------- normalize + transpose: x (B,C,N) fp32 -> xnt (B,N,C) bf16 --------
__global__ __launch_bounds__(256) void norm_transpose_kernel(
    const float* __restrict__ x, const float* __restrict__ scale,
    const float* __restrict__ shift, unsigned short* __restrict__ xnt) {
  const int b = blockIdx.z;
  const int n0 = blockIdx.x * 64;
  const int c0 = blockIdx.y * 64;
  const int t = threadIdx.x;
  __shared__ unsigned short tile[64][65];
  {
    const int cl = t >> 2;
    const int nc = (t & 3) * 16;
    const int c = c0 + cl;
    const float* xp = x + ((long long)b * 512 + c) * 4096 + n0 + nc;
    const float sc = scale[b * 512 + c];
    const float sh = shift[b * 512 + c];
#pragma unroll
    for (int j = 0; j < 16; j += 4) {
      float4 v = *(const float4*)(xp + j);
      tile[cl][nc + j + 0] = f2bf(v.x * sc + sh);
      tile[cl][nc + j + 1] = f2bf(v.y * sc + sh);
      tile[cl][nc + j + 2] = f2bf(v.z * sc + sh);
      tile[cl][nc + j + 3] = f2bf(v.w * sc + sh);
    }
  }
  __syncthreads();
  {
    const int nl = t >> 2;
    const int cc = (t & 3) * 16;
    union { unsigned short u[16]; uint4 q[2]; } o;
#pragma unroll
    for (int j = 0; j < 16; ++j) o.u[j] = tile[cc + j][nl];
    unsigned short* op = xnt + ((long long)b * 4096 + n0 + nl) * 512 + c0 + cc;
    *((uint4*)op) = o.q[0];
    *((uint4*)op + 1) = o.q[1];
  }
}

// ---------------- TN GEMM, m97 structure -----------------------------------
// C[m,n] = sum_k A[m*lda+k] * B[n*ldb+k]   (A,B bf16, K-contiguous rows)
// EPI: 0 = bf16 out; 1 = bf16 out + bias[n]; 2 = bf16 out + bias[m];
//      3 = fp32 out + res[m*ldc+n] (residual)
template <int EPI>
__global__ __launch_bounds__(256) void gemm_tn_kernel(
    const unsigned short* __restrict__ A, const unsigned short* __restrict__ B,
    void* __restrict__ C, const float* __restrict__ bias,
    const float* __restrict__ res, int lda, int ldb, int ldc, int K,
    long long sA, long long sB, long long sC, long long sRes) {
  const int tid = threadIdx.x;
  const int lane = tid & 63;
  const int wave = tid >> 6;
  const int m0 = blockIdx.x * 128;
  const int n0 = blockIdx.y * 128;
  const int bz = blockIdx.z;
  A += (long long)bz * sA;
  B += (long long)bz * sB;

  __shared__ unsigned short As[128 * 64];
  __shared__ unsigned short Bs[128 * 64];

  floatx4 acc[4][4];
#pragma unroll
  for (int i = 0; i < 4; ++i)
#pragma unroll
    for (int j = 0; j < 4; ++j) acc[i][j] = (floatx4){0.f, 0.f, 0.f, 0.f};

  const unsigned short* ag[4];
  const unsigned short* bg[4];
  unsigned ldsoff[4];
#pragma unroll
  for (int i = 0; i < 4; ++i) {
    const int idx = i * 256 + tid;   // granule id (16B) within 128x64 tile
    const int r = idx >> 3;          // row 0..127
    const int g = idx & 7;           // 16B granule within row
    ag[i] = A + (long long)(m0 + r) * lda + g * 8;
    bg[i] = B + (long long)(n0 + r) * ldb + g * 8;
    ldsoff[i] = (unsigned)(i * 256 + wave * 64) * 8;  // wave-uniform LDS base
  }

  const int l15 = lane & 15;
  const int kq = (lane >> 4) * 8;
  const int wm = (wave >> 1) * 64;
  const int wn = (wave & 1) * 64;

  for (int k0 = 0; k0 < K; k0 += 64) {
#pragma unroll
    for (int i = 0; i < 4; ++i) {
      __builtin_amdgcn_global_load_lds(
          (const __attribute__((address_space(1))) void*)(ag[i] + k0),
          (__attribute__((address_space(3))) void*)(As + ldsoff[i]), 16, 0, 0);
      __builtin_amdgcn_global_load_lds(
          (const __attribute__((address_space(1))) void*)(bg[i] + k0),
          (__attribute__((address_space(3))) void*)(Bs + ldsoff[i]), 16, 0, 0);
    }
    __syncthreads();
#pragma unroll
    for (int kk = 0; kk < 64; kk += 32) {
      short8 af[4], bfr[4];
#pragma unroll
      for (int mt = 0; mt < 4; ++mt)
        af[mt] = *(const short8*)&As[(wm + mt * 16 + l15) * 64 + kk + kq];
#pragma unroll
      for (int nt = 0; nt < 4; ++nt)
        bfr[nt] = *(const short8*)&Bs[(wn + nt * 16 + l15) * 64 + kk + kq];
#pragma unroll
      for (int mt = 0; mt < 4; ++mt)
#pragma unroll
        for (int nt = 0; nt < 4; ++nt)
          acc[mt][nt] = __builtin_amdgcn_mfma_f32_16x16x32_bf16(
              af[mt], bfr[nt], acc[mt][nt], 0, 0, 0);
    }
    __syncthreads();
  }

  const int r0 = (lane >> 4) * 4;
#pragma unroll
  for (int mt = 0; mt < 4; ++mt) {
#pragma unroll
    for (int nt = 0; nt < 4; ++nt) {
      const int n = n0 + wn + nt * 16 + l15;
      float bn = 0.f;
      if (EPI == 1) bn = bias[n];
#pragma unroll
      for (int r = 0; r < 4; ++r) {
        const int m = m0 + wm + mt * 16 + r0 + r;
        float v = acc[mt][nt][r];
        if (EPI == 1) v += bn;
        if (EPI == 2) v += bias[m];
        if (EPI == 3) {
          float* o = (float*)C + (long long)bz * sC;
          const float* rr = res + (long long)bz * sRes;
          const long long off = (long long)m * ldc + n;
          o[off] = v + rr[off];
        } else {
          unsigned short* o = (unsigned short*)C + (long long)bz * sC;
          o[(long long)m * ldc + n] = f2bf(v);
        }
      }
    }
  }
}

// ---------------- row softmax over S (bf16, in place) ----------------------
__global__ __launch_bounds__(256) void softmax_kernel(unsigned short* __restrict__ S) {
  const long long row = (long long)blockIdx.y * 4096 + blockIdx.x;
  unsigned short* p = S + row * 4096;
  const int t = threadIdx.x;
  const int lane = t & 63, wave = t >> 6;
  uint4 qa = *((const uint4*)p + t * 2);
  uint4 qb = *((const uint4*)p + t * 2 + 1);
  unsigned int ua[8] = {qa.x, qa.y, qa.z, qa.w, qb.x, qb.y, qb.z, qb.w};
  float vals[16];
#pragma unroll
  for (int j = 0; j < 8; ++j) {
    vals[2 * j]     = bf2f((unsigned short)(ua[j] & 0xffffu));
    vals[2 * j + 1] = bf2f((unsigned short)(ua[j] >> 16));
  }
  float vmax = -3.0e38f;
#pragma unroll
  for (int j = 0; j < 16; ++j) vmax = fmaxf(vmax, vals[j]);
  for (int off = 32; off; off >>= 1) vmax = fmaxf(vmax, __shfl_down(vmax, off));
  __shared__ float sred[4];
  if (lane == 0) sred[wave] = vmax;
  __syncthreads();
  vmax = fmaxf(fmaxf(sred[0], sred[1]), fmaxf(sred[2], sred[3]));
  const float SCL = 0.044194173824159216f;  // 1/sqrt(512)
  float sum = 0.f;
#pragma unroll
  for (int j = 0; j < 16; ++j) {
    float e = __expf((vals[j] - vmax) * SCL);
    vals[j] = e;
    sum += e;
  }
  for (int off = 32; off; off >>= 1) sum += __shfl_down(sum, off);
  __syncthreads();
  if (lane == 0) sred[wave] = sum;
  __syncthreads();
  const float inv = 1.f / (sred[0] + sred[1] + sred[2] + sred[3]);
  unsigned int ou[8];
#pragma unroll
  for (int j = 0; j < 8; ++j) {
    unsigned short lo = f2bf(vals[2 * j] * inv);
    unsigned short hi = f2bf(vals[2 * j + 1] * inv);
    ou[j] = (unsigned)lo | ((unsigned)hi << 16);
  }
  uint4 oa = {ou[0], ou[1], ou[2], ou[3]}, ob = {ou[4], ou[5], ou[6], ou[7]};
  *((uint4*)p + t * 2) = oa;
  *((uint4*)p + t * 2 + 1) = ob;
}

extern "C" void kernel_launch(void* const* d_in, const int* in_sizes, int n_in,
                              void* d_out, int out_size, void* d_ws, size_t ws_size,
                              hipStream_t stream) {
  const float* x     = (const float*)d_in[0];
  const float* gamma = (const float*)d_in[1];
  const float* beta  = (const float*)d_in[2];
  const float* wq    = (const float*)d_in[3];
  const float* bq    = (const float*)d_in[4];
  const float* wk    = (const float*)d_in[5];
  const float* bk    = (const float*)d_in[6];
  const float* wv    = (const float*)d_in[7];
  const float* bv    = (const float*)d_in[8];
  float* out = (float*)d_out;

  char* ws = (char*)d_ws;
  float* scale = (float*)ws;                       // 4*512 fp32
  float* shift = (float*)(ws + 8192);              // 4*512 fp32
  unsigned short* w16 = (unsigned short*)(ws + 16384);          // 3 * 512*512 bf16
  unsigned short* xnt = (unsigned short*)(ws + 1589248);        // (B,N,C) bf16
  const long long sTok = 4096LL * 512;                          // per-batch elems
  unsigned short* qt = xnt + 4 * sTok;
  unsigned short* kt = qt + 4 * sTok;
  unsigned short* vv = kt + 4 * sTok;
  unsigned short* S  = vv + 4 * sTok;              // byte off 68698112

  gn_stats_kernel<<<128, 256, 0, stream>>>(x, gamma, beta, scale, shift);
  wcvt_kernel<<<dim3(256, 3), 256, 0, stream>>>(wq, wk, wv, w16);
  norm_transpose_kernel<<<dim3(64, 8, 4), 256, 0, stream>>>(x, scale, shift, xnt);

  // Qt (B,N,C) = Xnt * Wq^T   (bias over col = output channel)
  gemm_tn_kernel<1><<<dim3(32, 4, 4), 256, 0, stream>>>(
      xnt, w16, qt, bq, nullptr, 512, 512, 512, 512, sTok, 0, sTok, 0);
  gemm_tn_kernel<1><<<dim3(32, 4, 4), 256, 0, stream>>>(
      xnt, w16 + 262144, kt, bk, nullptr, 512, 512, 512, 512, sTok, 0, sTok, 0);
  // V (B,C,N) = Wv * Xn       (bias over row = output channel)
  gemm_tn_kernel<2><<<dim3(4, 32, 4), 256, 0, stream>>>(
      w16 + 524288, xnt, vv, bv, nullptr, 512, 512, 4096, 512, 0, sTok, sTok, 0);

  const long long sS = 4096LL * 4096;
  const bool full = ws_size >= 202915840ULL;  // S for all 4 batches fits
  if (full) {
    gemm_tn_kernel<0><<<dim3(32, 32, 4), 256, 0, stream>>>(
        qt, kt, S, nullptr, nullptr, 512, 512, 4096, 512, sTok, sTok, sS, 0);
    softmax_kernel<<<dim3(4096, 4), 256, 0, stream>>>(S);
    gemm_tn_kernel<3><<<dim3(4, 32, 4), 256, 0, stream>>>(
        vv, S, out, nullptr, x, 4096, 4096, 4096, 4096, sTok, sS, sTok, sTok);
  } else {
    for (int b = 0; b < 4; ++b) {
      gemm_tn_kernel<0><<<dim3(32, 32, 1), 256, 0, stream>>>(
          qt + b * sTok, kt + b * sTok, S, nullptr, nullptr, 512, 512, 4096, 512, 0, 0, 0, 0);
      softmax_kernel<<<dim3(4096, 1), 256, 0, stream>>>(S);
      gemm_tn_kernel<3><<<dim3(4, 32, 1), 256, 0, stream>>>(
          vv + b * sTok, S, out + (long long)b * sTok, nullptr, x + (long long)b * sTok,
          4096, 4096, 4096, 4096, 0, 0, 0, 0);
    }
  }
}